// Round 8
// baseline (1042.535 us; speedup 1.0000x reference)
//
#include <hip/hip_runtime.h>
#include <math.h>

#define ITERS 30

// ws float offsets. ws[0..1023] ints = flags (memset 0 each launch):
//   cnt[b*32+s]: strip arrival flags (epoch it+1); cnt[256+b]: gsum-ready flag;
//   cnt[512+bb]: final-done flags.
#define PENDf  1024      // [b][s][m] strip partials: 8*32*512
#define GSUMf  132096    // [b][m] combined: 8*512
#define BPARTf 136192    // [bb][8] epilogue partials: 256*8

#define LN2f    0.69314718055994530942f
#define K2c     2.40449173481494868463f   // 1/(0.6*ln2)
#define KCc     144.269504088896340736f   // 100/ln2
#define CKCc   -0.98039215686274509804f   // CNEG*KC = -eps*damping*100
#define EMDKc   0.01960784313725490196f   // eps*damping/rho (exp2 coeff for emd terms)

__device__ __forceinline__ float fexp2(float x){ return __builtin_amdgcn_exp2f(x); }
__device__ __forceinline__ float flog2(float x){ return __builtin_amdgcn_logf(x); }
__device__ __forceinline__ float fsq(float x){ return __builtin_amdgcn_sqrtf(x); }

__device__ __forceinline__ void st_atm(float* p, float v){
  __hip_atomic_store(p, v, __ATOMIC_RELAXED, __HIP_MEMORY_SCOPE_AGENT);
}
__device__ __forceinline__ float ld_atm(const float* p){
  return __hip_atomic_load(p, __ATOMIC_RELAXED, __HIP_MEMORY_SCOPE_AGENT);
}
__device__ __forceinline__ void st_flag(int* p, int v){
  __hip_atomic_store(p, v, __ATOMIC_RELAXED, __HIP_MEMORY_SCOPE_AGENT);
}
__device__ __forceinline__ int ld_flag(const int* p){
  return __hip_atomic_load(p, __ATOMIC_RELAXED, __HIP_MEMORY_SCOPE_AGENT);
}

__device__ __forceinline__ float wave_max(float v){
  #pragma unroll
  for (int off = 1; off < 64; off <<= 1) v = fmaxf(v, __shfl_xor(v, off));
  return v;
}
__device__ __forceinline__ float wave_sum(float v){
  #pragma unroll
  for (int off = 1; off < 64; off <<= 1) v += __shfl_xor(v, off);
  return v;
}

// Block bb: batch b = bb&7, strip s = bb>>3 (rows n = s*128 + w*8 + r).
// Combiner = strip 0 of each batch (bb < 8, one per XCD under round-robin).
// Lane l, slot k -> m = k*64+l. nK[r][k] = -KC*2^(K2*d(n,m)): 64 VGPRs —
// waves_per_eu(4,4) grants the 128-VGPR budget so it stays in registers.
__global__ __attribute__((amdgpu_flat_work_group_size(1024,1024), amdgpu_waves_per_eu(4,4)))
void k_sink(const float* __restrict__ A, const float* __restrict__ pts,
            float* __restrict__ ws, float* __restrict__ out){
  __shared__ float2 pms[512 * 17];   // [row][wave] merge buffer; slot 16 = combine half
  __shared__ float g_lds[512];
  __shared__ float red[96];
  float* pmsf = (float*)pms;
  const int tid = threadIdx.x, w = tid >> 6, l = tid & 63;
  const int bb = blockIdx.x, b = bb & 7, s = bb >> 3;
  const bool comb = (s == 0);
  int* cnt   = (int*)ws;
  int* flagB = cnt + b * 32;
  int* gflag = cnt + 256 + b;
  float* pend = ws + PENDf + b * 32 * 512;   // [s][m]
  float* gsum = ws + GSUMf + b * 512;

  float nK[64], laK[8], Lf[8], shg[8];

  // ---- prologue: cost tile + log-mass
  {
    const float2* p2 = (const float2*)(pts + b*1024);
    float px[8], py[8];
    #pragma unroll
    for (int k = 0; k < 8; ++k){
      float2 pv = p2[k*64 + l];
      px[k] = pv.x * (1.f/512.f);
      py[k] = pv.y * (1.f/512.f);
    }
    #pragma unroll
    for (int r = 0; r < 8; ++r){
      int n = s*128 + w*8 + r;
      float xn = (float)((n & 63) + 1) * (1.f/64.f);
      float yn = (float)((n >> 6) + 1) * (1.f/64.f);
      laK[r] = flog2(A[b*4096 + n] + 1e-20f) + KCc;
      #pragma unroll
      for (int k = 0; k < 8; ++k){
        float dx = xn - px[k], dy = yn - py[k];
        float d2 = __builtin_fmaf(dy, dy, __builtin_fmaf(dx, dx, 1e-12f));
        nK[r*8 + k] = -KCc * fexp2(fsq(d2) * K2c);
      }
    }
  }

  // ---- 30 x { strip partials -> flag -> combiner sums -> gflag -> f-update }
  #pragma unroll 1
  for (int it = 0; it < ITERS; ++it){
    // A: per-strip g-partials (iter0: exact (M,S); else: shifted plain sums)
    if (it == 0){
      #pragma unroll
      for (int k = 0; k < 8; ++k){
        float y[8], pm = -INFINITY;
        #pragma unroll
        for (int r = 0; r < 8; ++r){ y[r] = laK[r] + nK[r*8 + k]; pm = fmaxf(pm, y[r]); }
        float ps = 0.f;
        #pragma unroll
        for (int r = 0; r < 8; ++r) ps += fexp2(y[r] - pm);
        pms[(k*64 + l)*17 + w] = make_float2(pm, ps);
      }
      __syncthreads();
      if (tid < 512){
        float M = -INFINITY, S = 0.f;
        float2 v[16];
        #pragma unroll
        for (int q = 0; q < 16; ++q){ v[q] = pms[tid*17 + q]; M = fmaxf(M, v[q].x); }
        #pragma unroll
        for (int q = 0; q < 16; ++q) S += v[q].y * fexp2(v[q].x - M);
        st_atm(&pend[s*512 + tid], M + flog2(S));
      }
    } else {
      float pr[8];
      #pragma unroll
      for (int r = 0; r < 8; ++r) pr[r] = __builtin_fmaf(CKCc, Lf[r], laK[r]);
      #pragma unroll
      for (int k = 0; k < 8; ++k){
        float sh = shg[k], sv = 0.f;
        #pragma unroll
        for (int r = 0; r < 8; ++r) sv += fexp2(pr[r] + nK[r*8 + k] - sh);
        pmsf[(k*64 + l)*17 + w] = sv;
      }
      __syncthreads();
      if (tid < 512){
        float cb = 0.f;
        #pragma unroll
        for (int q = 0; q < 16; ++q) cb += pmsf[tid*17 + q];
        st_atm(&pend[s*512 + tid], cb);
      }
    }
    __syncthreads();                       // drains all partial stores (vmcnt 0)
    if (tid == 0) st_flag(&flagB[s], it + 1);

    // B: combine (single writer) / wait on gflag (readers)
    if (comb){
      if (tid < 32){
        int spins = 0;
        while (ld_flag(&flagB[tid]) < it + 1){
          __builtin_amdgcn_s_sleep(1);
          if (++spins > (1 << 20)) break;  // fail visibly, never hang
        }
      }
      __syncthreads();
      int m = tid & 511, h = tid >> 9;     // halves: h=0 strips 0-15, h=1 strips 16-31
      const float* pp = pend + h*16*512 + m;
      if (it == 0){
        float M = -INFINITY, S = 0.f;
        #pragma unroll
        for (int j = 0; j < 16; ++j){
          float L = ld_atm(&pp[j*512]);
          float Mn = fmaxf(M, L);
          S = __builtin_fmaf(S, fexp2(M - Mn), fexp2(L - Mn));
          M = Mn;
        }
        if (h) pms[m*17 + 16] = make_float2(M, S);
        __syncthreads();
        if (tid < 512){
          float2 o = pms[m*17 + 16];
          float Mn = fmaxf(M, o.x);
          float St = __builtin_fmaf(S, fexp2(M - Mn), o.y * fexp2(o.x - Mn));
          float Lg = Mn + flog2(St);
          st_atm(&gsum[m], Lg);
          g_lds[m] = Lg;
        }
      } else {
        float S = 0.f;
        #pragma unroll
        for (int j = 0; j < 16; ++j) S += ld_atm(&pp[j*512]);
        if (h) pmsf[m*17 + 16] = S;
        __syncthreads();
        if (tid < 512){
          float St = S + pmsf[m*17 + 16];
          st_atm(&gsum[m], St);
          g_lds[m] = St;
        }
      }
      __syncthreads();                     // drains gsum stores + g_lds visible
      if (tid == 0) st_flag(gflag, it + 1);
    } else {
      if (tid == 0){
        int spins = 0;
        while (ld_flag(gflag) < it + 1){
          __builtin_amdgcn_s_sleep(1);
          if (++spins > (1 << 20)) break;
        }
      }
      __syncthreads();
      if (tid < 512) g_lds[tid] = ld_atm(&gsum[tid]);
      __syncthreads();
    }

    // C: shg update + f-update (identical math on every block)
    float g2t[8];
    #pragma unroll
    for (int k = 0; k < 8; ++k){
      float v  = g_lds[k*64 + l];
      float Lg = (it == 0) ? v : shg[k] + flog2(v);
      shg[k] = Lg;
      g2t[k] = __builtin_fmaf(CKCc, Lg, KCc);
    }
    if (it == 0){
      #pragma unroll
      for (int r = 0; r < 8; ++r){
        float y[8], cm = -INFINITY;
        #pragma unroll
        for (int k = 0; k < 8; ++k){ y[k] = g2t[k] + nK[r*8 + k]; cm = fmaxf(cm, y[k]); }
        float M = wave_max(cm);
        float sv = 0.f;
        #pragma unroll
        for (int k = 0; k < 8; ++k) sv += fexp2(y[k] - M);
        Lf[r] = M + flog2(wave_sum(sv));
      }
    } else {
      #pragma unroll
      for (int r = 0; r < 8; ++r){
        float sh = Lf[r], sv = 0.f;
        #pragma unroll
        for (int k = 0; k < 8; ++k) sv += fexp2(g2t[k] + nK[r*8 + k] - sh);
        Lf[r] = sh + flog2(wave_sum(sv));
      }
    }
  }

  // ---- epilogue: PI losses (z = CKC*(Lf[r]+shg[k]) + laK[r] + nK)
  float ent = 0.f, pix = 0.f, emdf = 0.f, csum[8];
  #pragma unroll
  for (int k = 0; k < 8; ++k) csum[k] = 0.f;
  #pragma unroll
  for (int r = 0; r < 8; ++r){
    float An = fexp2(laK[r] - KCc);
    float rs = 0.f;
    #pragma unroll
    for (int k = 0; k < 8; ++k){
      float z = __builtin_fmaf(CKCc, Lf[r] + shg[k], laK[r]) + nK[r*8 + k];
      float p = fexp2(z);
      rs += p; csum[k] += p;
      float q = p + 1e-20f;
      ent = __builtin_fmaf(q * LN2f, flog2(q), ent);
    }
    float RS = wave_sum(rs);
    if (l == 0){
      pix  += fabsf(RS - An);
      emdf += An * (1.f - fexp2(EMDKc * Lf[r]));
    }
  }
  // colsum exchange: strips store plain sums; combiner sums -> point loss
  #pragma unroll
  for (int k = 0; k < 8; ++k) pmsf[(k*64 + l)*17 + w] = csum[k];
  __syncthreads();
  if (tid < 512){
    float cb = 0.f;
    #pragma unroll
    for (int q = 0; q < 16; ++q) cb += pmsf[tid*17 + q];
    st_atm(&pend[s*512 + tid], cb);
  }
  __syncthreads();
  if (tid == 0) st_flag(&flagB[s], ITERS + 1);

  float pnt = 0.f, emdg = 0.f;
  if (comb){
    if (tid < 32){
      int spins = 0;
      while (ld_flag(&flagB[tid]) < ITERS + 1){
        __builtin_amdgcn_s_sleep(1);
        if (++spins > (1 << 20)) break;
      }
    }
    __syncthreads();
    int m = tid & 511, h = tid >> 9;
    const float* pp = pend + h*16*512 + m;
    float S = 0.f;
    #pragma unroll
    for (int j = 0; j < 16; ++j) S += ld_atm(&pp[j*512]);
    if (h) pmsf[m*17 + 16] = S;
    __syncthreads();
    if (tid < 512) pnt = fabsf(S + pmsf[tid*17 + 16] - 1.f);   // once per batch
    if (w == 0){
      float acc = 0.f;
      #pragma unroll
      for (int k = 0; k < 8; ++k) acc += 1.f - fexp2(EMDKc * shg[k]);
      emdg = acc;
    }
  }

  ent = wave_sum(ent); pix = wave_sum(pix); emdf = wave_sum(emdf);
  pnt = wave_sum(pnt); emdg = wave_sum(emdg);
  if (l == 0){
    red[w*5+0] = ent; red[w*5+1] = pix; red[w*5+2] = emdf; red[w*5+3] = pnt; red[w*5+4] = emdg;
  }
  __syncthreads();
  if (tid == 0){
    float a0=0,a1=0,a2=0,a3=0,a4=0;
    for (int q = 0; q < 16; ++q){
      a0 += red[q*5+0]; a1 += red[q*5+1]; a2 += red[q*5+2]; a3 += red[q*5+3]; a4 += red[q*5+4];
    }
    float* bp = ws + BPARTf + bb*8;
    st_atm(&bp[0], a0); st_atm(&bp[1], a1); st_atm(&bp[2], a2);
    st_atm(&bp[3], a3); st_atm(&bp[4], a4);
  }

  __syncthreads();                         // drain BPART stores
  if (tid == 0) st_flag(&cnt[512 + bb], 1);
  if (bb != 0) return;

  if (tid < 256){
    int spins = 0;
    while (ld_flag(&cnt[512 + tid]) < 1){
      __builtin_amdgcn_s_sleep(1);
      if (++spins > (1 << 20)) break;
    }
  }
  __syncthreads();
  {
    float v0=0,v1=0,v2=0,v3=0,v4=0;
    if (tid < 256){
      const float* bp = ws + BPARTf + tid*8;
      v0=ld_atm(&bp[0]); v1=ld_atm(&bp[1]); v2=ld_atm(&bp[2]);
      v3=ld_atm(&bp[3]); v4=ld_atm(&bp[4]);
    }
    v0=wave_sum(v0); v1=wave_sum(v1); v2=wave_sum(v2); v3=wave_sum(v3); v4=wave_sum(v4);
    if (l == 0){
      red[w*5+0]=v0; red[w*5+1]=v1; red[w*5+2]=v2; red[w*5+3]=v3; red[w*5+4]=v4;
    }
    __syncthreads();
    if (tid == 0){
      float E=0,PX=0,EF=0,PT=0,EG=0;
      for (int q = 0; q < 16; ++q){
        E += red[q*5+0]; PX += red[q*5+1]; EF += red[q*5+2]; PT += red[q*5+3]; EG += red[q*5+4];
      }
      float emd = 0.5f * (EF + EG);
      out[0] = emd + 0.1f * (PX + PT) + 0.01f * (E * (1.f / (4096.f * 512.f)));
    }
  }
}

extern "C" void kernel_launch(void* const* d_in, const int* in_sizes, int n_in,
                              void* d_out, int out_size, void* d_ws, size_t ws_size,
                              hipStream_t stream) {
  const float* A   = (const float*)d_in[0];   // predict_map [8,1,64,64]
  const float* pts = (const float*)d_in[1];   // points [8,512,2]
  float* ws  = (float*)d_ws;
  float* out = (float*)d_out;

  hipMemsetAsync(d_ws, 0, 4096, stream);      // zero all flags every call
  k_sink<<<256, 1024, 0, stream>>>(A, pts, ws, out);
}

// Round 9
// 661.269 us; speedup vs baseline: 1.5766x; 1.5766x over previous
//
#include <hip/hip_runtime.h>
#include <math.h>

// ws float offsets (no flags, no atomics anywhere)
#define PEND0f 0         // [b][s][m] partials, parity 0: 8*32*512
#define PEND1f 131072    // parity 1
#define SHG0f  262144    // [b][m] column-LSE shg, parity 0: 8*512
#define SHG1f  266240    // parity 1
#define LFf    270336    // [b][n] row-LSE Lf: 8*4096
#define BPARTf 303104    // [bb][8] epilogue partials: 256*8

#define LN2f    0.69314718055994530942f
#define K2c     2.40449173481494868463f   // 1/(0.6*ln2)
#define KCc     144.269504088896340736f   // 100/ln2
#define CKCc   -0.98039215686274509804f   // -eps*damping*100 (log2 domain)
#define EMDKc   0.01960784313725490196f   // eps*damping/rho

__device__ __forceinline__ float fexp2(float x){ return __builtin_amdgcn_exp2f(x); }
__device__ __forceinline__ float flog2(float x){ return __builtin_amdgcn_logf(x); }
__device__ __forceinline__ float fsq(float x){ return __builtin_amdgcn_sqrtf(x); }

__device__ __forceinline__ float wave_max(float v){
  #pragma unroll
  for (int off = 1; off < 64; off <<= 1) v = fmaxf(v, __shfl_xor(v, off));
  return v;
}
__device__ __forceinline__ float wave_sum(float v){
  #pragma unroll
  for (int off = 1; off < 64; off <<= 1) v += __shfl_xor(v, off);
  return v;
}

// shared tile helper: block bb -> batch b=bb&7 (XCD co-location), strip s=bb>>3,
// rows n = s*128 + w*8 + r; lane l, slot k -> m = k*64+l.
// nK[r*8+k] = -KC * 2^(K2*d(n,m)); laK[r] = log2(A[n]+1e-20) + KC.
__device__ __forceinline__ void build_tile(const float* A, const float* pts,
                                           int b, int s, int w, int l,
                                           float* nK, float* laK){
  const float2* p2 = (const float2*)(pts + b*1024);
  float px[8], py[8];
  #pragma unroll
  for (int k = 0; k < 8; ++k){
    float2 pv = p2[k*64 + l];
    px[k] = pv.x * (1.f/512.f);
    py[k] = pv.y * (1.f/512.f);
  }
  #pragma unroll
  for (int r = 0; r < 8; ++r){
    int n = s*128 + w*8 + r;
    float xn = (float)((n & 63) + 1) * (1.f/64.f);
    float yn = (float)((n >> 6) + 1) * (1.f/64.f);
    laK[r] = flog2(A[b*4096 + n] + 1e-20f) + KCc;
    #pragma unroll
    for (int k = 0; k < 8; ++k){
      float dx = xn - px[k], dy = yn - py[k];
      float d2 = __builtin_fmaf(dy, dy, __builtin_fmaf(dx, dx, 1e-12f));
      nK[r*8 + k] = -KCc * fexp2(fsq(d2) * K2c);
    }
  }
}

// ---- prologue: per-strip EXACT (M,S) column-LSE partials from f0=0 -> PEND0
__global__ __launch_bounds__(1024, 4) void k_pro(const float* __restrict__ A,
                                                 const float* __restrict__ pts,
                                                 float* __restrict__ ws){
  __shared__ float2 pms[512 * 17];
  const int tid = threadIdx.x, w = tid >> 6, l = tid & 63;
  const int bb = blockIdx.x, b = bb & 7, s = bb >> 3;
  float nK[64], laK[8];
  build_tile(A, pts, b, s, w, l, nK, laK);
  #pragma unroll
  for (int k = 0; k < 8; ++k){
    float y[8], pm = -INFINITY;
    #pragma unroll
    for (int r = 0; r < 8; ++r){ y[r] = laK[r] + nK[r*8 + k]; pm = fmaxf(pm, y[r]); }
    float ps = 0.f;
    #pragma unroll
    for (int r = 0; r < 8; ++r) ps += fexp2(y[r] - pm);
    pms[(k*64 + l)*17 + w] = make_float2(pm, ps);
  }
  __syncthreads();
  if (tid < 512){
    float2 v[16]; float M = -INFINITY, S = 0.f;
    #pragma unroll
    for (int q = 0; q < 16; ++q){ v[q] = pms[tid*17 + q]; M = fmaxf(M, v[q].x); }
    #pragma unroll
    for (int q = 0; q < 16; ++q) S += v[q].y * fexp2(v[q].x - M);
    ws[PEND0f + (b*32 + s)*512 + tid] = M + flog2(S);
  }
}

// ---- one Sinkhorn iteration (it = 1..30): combine -> g_t; f-update -> f_t;
//      if it<30 write next g-partials. All cross-block data via kernel boundary.
__global__ __launch_bounds__(1024, 4) void k_it(const float* __restrict__ A,
                                                const float* __restrict__ pts,
                                                float* __restrict__ ws, int it){
  __shared__ float2 pms[512 * 17];
  __shared__ float g_lds[512];
  float* pmsf = (float*)pms;
  const int tid = threadIdx.x, w = tid >> 6, l = tid & 63;
  const int bb = blockIdx.x, b = bb & 7, s = bb >> 3;
  const float* pendIn  = ws + (((it + 1) & 1) ? PEND1f : PEND0f) + b*32*512;
  float*       pendOut = ws + ((it & 1)       ? PEND1f : PEND0f) + b*32*512;
  const float* shgIn   = ws + (((it + 1) & 1) ? SHG1f : SHG0f) + b*512;
  float*       shgOut  = ws + ((it & 1)       ? SHG1f : SHG0f) + b*512;
  float*       wsLf    = ws + LFf + b*4096;

  float nK[64], laK[8];
  build_tile(A, pts, b, s, w, l, nK, laK);

  // combine 32 strip partials -> Lg (column LSE) in g_lds, redundantly per block
  {
    int m = tid & 511, h = tid >> 9;
    const float* pp = pendIn + h*16*512 + m;
    if (it == 1){
      float M = -INFINITY, S = 0.f;
      #pragma unroll
      for (int j = 0; j < 16; ++j){
        float L = pp[j*512];
        float Mn = fmaxf(M, L);
        S = __builtin_fmaf(S, fexp2(M - Mn), fexp2(L - Mn));
        M = Mn;
      }
      if (h) pms[m*17 + 16] = make_float2(M, S);
      __syncthreads();
      if (tid < 512){
        float2 o = pms[m*17 + 16];
        float Mn = fmaxf(M, o.x);
        float St = __builtin_fmaf(S, fexp2(M - Mn), o.y * fexp2(o.x - Mn));
        g_lds[m] = Mn + flog2(St);
      }
    } else {
      float S = 0.f;
      #pragma unroll
      for (int j = 0; j < 16; ++j) S += pp[j*512];
      if (h) pmsf[m*17 + 16] = S;
      __syncthreads();
      if (tid < 512) g_lds[m] = shgIn[m] + flog2(S + pmsf[m*17 + 16]);
    }
  }
  __syncthreads();
  if (s == 0 && tid < 512) shgOut[tid] = g_lds[tid];   // for launch it+1 / epilogue

  float shk[8], g2t[8];
  #pragma unroll
  for (int k = 0; k < 8; ++k){
    shk[k] = g_lds[k*64 + l];
    g2t[k] = __builtin_fmaf(CKCc, shk[k], KCc);
  }

  // f-update (it==1 exact; else shifted by previous Lf from ws)
  float Lfr[8];
  if (it == 1){
    #pragma unroll
    for (int r = 0; r < 8; ++r){
      float y[8], cm = -INFINITY;
      #pragma unroll
      for (int k = 0; k < 8; ++k){ y[k] = g2t[k] + nK[r*8 + k]; cm = fmaxf(cm, y[k]); }
      float M = wave_max(cm);
      float sv = 0.f;
      #pragma unroll
      for (int k = 0; k < 8; ++k) sv += fexp2(y[k] - M);
      Lfr[r] = M + flog2(wave_sum(sv));
    }
  } else {
    #pragma unroll
    for (int r = 0; r < 8; ++r){
      float sh = wsLf[s*128 + w*8 + r];   // wave-uniform broadcast load
      float sv = 0.f;
      #pragma unroll
      for (int k = 0; k < 8; ++k) sv += fexp2(g2t[k] + nK[r*8 + k] - sh);
      Lfr[r] = sh + flog2(wave_sum(sv));
    }
  }
  if (l == 0){
    #pragma unroll
    for (int r = 0; r < 8; ++r) wsLf[s*128 + w*8 + r] = Lfr[r];
  }

  // next-iteration g-partials (shifted plain sums), skip on the last iteration
  if (it < 30){
    float pr[8];
    #pragma unroll
    for (int r = 0; r < 8; ++r) pr[r] = __builtin_fmaf(CKCc, Lfr[r], laK[r]);
    #pragma unroll
    for (int k = 0; k < 8; ++k){
      float sh = shk[k], sv = 0.f;
      #pragma unroll
      for (int r = 0; r < 8; ++r) sv += fexp2(pr[r] + nK[r*8 + k] - sh);
      pmsf[(k*64 + l)*17 + w] = sv;
    }
    __syncthreads();
    if (tid < 512){
      float cb = 0.f;
      #pragma unroll
      for (int q = 0; q < 16; ++q) cb += pmsf[tid*17 + q];
      pendOut[s*512 + tid] = cb;
    }
  }
}

// ---- epilogue: entropy / pixel / emd-f / emd-g per block; colsum partials
__global__ __launch_bounds__(1024, 4) void k_epi(const float* __restrict__ A,
                                                 const float* __restrict__ pts,
                                                 float* __restrict__ ws){
  __shared__ float2 pms[512 * 17];
  __shared__ float red[64];
  float* pmsf = (float*)pms;
  const int tid = threadIdx.x, w = tid >> 6, l = tid & 63;
  const int bb = blockIdx.x, b = bb & 7, s = bb >> 3;
  const float* shg  = ws + SHG0f + b*512;      // parity 30&1 = 0
  const float* wsLf = ws + LFf + b*4096;

  float nK[64], laK[8];
  build_tile(A, pts, b, s, w, l, nK, laK);

  float shk[8];
  #pragma unroll
  for (int k = 0; k < 8; ++k) shk[k] = shg[k*64 + l];

  float ent = 0.f, pix = 0.f, emdf = 0.f, csum[8];
  #pragma unroll
  for (int k = 0; k < 8; ++k) csum[k] = 0.f;
  #pragma unroll
  for (int r = 0; r < 8; ++r){
    float Lfr = wsLf[s*128 + w*8 + r];
    float An  = fexp2(laK[r] - KCc);
    float rs  = 0.f;
    #pragma unroll
    for (int k = 0; k < 8; ++k){
      float z = __builtin_fmaf(CKCc, Lfr + shk[k], laK[r]) + nK[r*8 + k];
      float p = fexp2(z);
      rs += p; csum[k] += p;
      float q = p + 1e-20f;
      ent = __builtin_fmaf(q * LN2f, flog2(q), ent);
    }
    float RS = wave_sum(rs);
    if (l == 0){
      pix  += fabsf(RS - An);
      emdf += An * (1.f - fexp2(EMDKc * Lfr));
    }
  }
  // colsum partials -> PEND1 (free after it=30), combined by k_fin
  #pragma unroll
  for (int k = 0; k < 8; ++k) pmsf[(k*64 + l)*17 + w] = csum[k];
  __syncthreads();
  if (tid < 512){
    float cb = 0.f;
    #pragma unroll
    for (int q = 0; q < 16; ++q) cb += pmsf[tid*17 + q];
    ws[PEND1f + (b*32 + s)*512 + tid] = cb;
  }
  float emdg = 0.f;
  if (s == 0 && w == 0){
    float acc = 0.f;
    #pragma unroll
    for (int k = 0; k < 8; ++k) acc += 1.f - fexp2(EMDKc * shk[k]);
    emdg = acc;                              // 64 lanes x 8 slots = all 512 m
  }
  ent = wave_sum(ent); pix = wave_sum(pix); emdf = wave_sum(emdf); emdg = wave_sum(emdg);
  if (l == 0){ red[w*4+0]=ent; red[w*4+1]=pix; red[w*4+2]=emdf; red[w*4+3]=emdg; }
  __syncthreads();
  if (tid == 0){
    float a0=0,a1=0,a2=0,a3=0;
    for (int q = 0; q < 16; ++q){ a0+=red[q*4]; a1+=red[q*4+1]; a2+=red[q*4+2]; a3+=red[q*4+3]; }
    float* bp = ws + BPARTf + bb*8;
    bp[0]=a0; bp[1]=a1; bp[2]=a2; bp[3]=a3;
  }
}

// ---- final: combine colsums (point loss) + block partials -> out[0]
__global__ __launch_bounds__(1024) void k_fin(const float* __restrict__ ws,
                                              float* __restrict__ out){
  __shared__ float red[80];
  const int tid = threadIdx.x, w = tid >> 6, l = tid & 63;
  float pnt = 0.f;
  #pragma unroll
  for (int q = 0; q < 4; ++q){
    int c = tid + q*1024;               // (b,m) pair
    int b = c >> 9, m = c & 511;
    float cs = 0.f;
    #pragma unroll
    for (int j = 0; j < 32; ++j) cs += ws[PEND1f + (b*32 + j)*512 + m];
    pnt += fabsf(cs - 1.f);
  }
  float e0=0.f, e1=0.f, e2=0.f, e3=0.f;
  if (tid < 256){
    const float* bp = ws + BPARTf + tid*8;
    e0=bp[0]; e1=bp[1]; e2=bp[2]; e3=bp[3];
  }
  pnt = wave_sum(pnt); e0 = wave_sum(e0); e1 = wave_sum(e1); e2 = wave_sum(e2); e3 = wave_sum(e3);
  if (l == 0){ red[w*5+0]=pnt; red[w*5+1]=e0; red[w*5+2]=e1; red[w*5+3]=e2; red[w*5+4]=e3; }
  __syncthreads();
  if (tid == 0){
    float PT=0,E=0,PX=0,EF=0,EG=0;
    for (int q = 0; q < 16; ++q){
      PT += red[q*5+0]; E += red[q*5+1]; PX += red[q*5+2]; EF += red[q*5+3]; EG += red[q*5+4];
    }
    float emd = 0.5f * (EF + EG);
    out[0] = emd + 0.1f * (PX + PT) + 0.01f * (E * (1.f / (4096.f * 512.f)));
  }
}

extern "C" void kernel_launch(void* const* d_in, const int* in_sizes, int n_in,
                              void* d_out, int out_size, void* d_ws, size_t ws_size,
                              hipStream_t stream) {
  const float* A   = (const float*)d_in[0];   // predict_map [8,1,64,64]
  const float* pts = (const float*)d_in[1];   // points [8,512,2]
  float* ws  = (float*)d_ws;
  float* out = (float*)d_out;

  k_pro<<<256, 1024, 0, stream>>>(A, pts, ws);
  for (int it = 1; it <= 30; ++it)
    k_it<<<256, 1024, 0, stream>>>(A, pts, ws, it);
  k_epi<<<256, 1024, 0, stream>>>(A, pts, ws);
  k_fin<<<1, 1024, 0, stream>>>(ws, out);
}